// Round 5
// baseline (621.753 us; speedup 1.0000x reference)
//
#include <hip/hip_runtime.h>
#include <stdint.h>

// ---------------------------------------------------------------------------
// RCNN post-process: refine bboxes, sort by score, greedy NMS (IoU >= 0.2),
// output = [refined boxes (N*4 floats)] ++ [keep mask as 0/1 floats (N)]
// ---------------------------------------------------------------------------

#define THR        0.2f
#define BORDER_EPS 1e-6f

typedef unsigned long long u64;
typedef unsigned int       u32;

__device__ __forceinline__ u64 rl64(u32 hi, u32 lo, int b) {
    return ((u64)__builtin_amdgcn_readlane(hi, (u32)b) << 32)
         |  (u64)__builtin_amdgcn_readlane(lo, (u32)b);
}

// ---------------- Kernel B: rank + refine + scatter (merged) ----------------
// 4 threads per box i; scores staged in LDS. q==0 thread computes the refined
// box (exact numpy op order, f64 exp) and writes both out[] and sboxes[rank].
// Block 0 also initializes the pad region of sboxes.
__global__ void k_rank(const float4* __restrict__ boxes,
                       const float4* __restrict__ deltas,
                       const float* __restrict__ scores,
                       float4* __restrict__ out,
                       float4* __restrict__ sboxes,
                       int* __restrict__ origIdx,
                       int n, int npad) {
    __shared__ __align__(16) float s[10016];
    int t = threadIdx.x;
    for (int idx = t; idx < n; idx += 256) s[idx] = scores[idx];
    if (blockIdx.x == 0) {
        int pi = n + t;
        if (pi < npad)
            sboxes[pi] = make_float4(-4.0e6f, -4.0e6f, -3.999999e6f, -3.999999e6f);
    }
    __syncthreads();

    int i = blockIdx.x * 64 + (t >> 2);
    if (i >= n) return;
    int q = t & 3;
    float si = s[i];
    int j0 = (n * q) >> 2;
    int j1 = (n * (q + 1)) >> 2;
    int cnt = 0;

    int ja = (j0 + 3) & ~3;
    int jb = j1 & ~3;
    for (int j = j0; j < ja && j < j1; ++j) {
        float sj = s[j];
        cnt += (sj > si) || (sj == si && j < i);
    }
    const float4* sv = (const float4*)s;
    for (int j4 = ja >> 2; j4 < (jb >> 2); ++j4) {
        float4 v = sv[j4];
        int j = j4 << 2;
        cnt += (v.x > si) || (v.x == si && (j + 0) < i);
        cnt += (v.y > si) || (v.y == si && (j + 1) < i);
        cnt += (v.z > si) || (v.z == si && (j + 2) < i);
        cnt += (v.w > si) || (v.w == si && (j + 3) < i);
    }
    for (int j = jb > j0 ? jb : j0; j < j1; ++j) {
        float sj = s[j];
        cnt += (sj > si) || (sj == si && j < i);
    }
    cnt += __shfl_xor(cnt, 1, 64);
    cnt += __shfl_xor(cnt, 2, 64);
    if (q == 0) {
        float4 b = boxes[i];
        float4 d = deltas[i];
        float x = __fmul_rn(__fadd_rn(b.x, b.z), 0.5f);
        float y = __fmul_rn(__fadd_rn(b.y, b.w), 0.5f);
        float w = __fsub_rn(b.z, b.x);
        float h = __fsub_rn(b.w, b.y);
        float nx = __fadd_rn(x, __fmul_rn(w, d.x));
        float ny = __fadd_rn(y, __fmul_rn(h, d.y));
        float ew = (float)exp((double)d.z);   // correctly-rounded f32 exp
        float eh = (float)exp((double)d.w);
        float nw = __fmul_rn(w, ew);
        float nh = __fmul_rn(h, eh);
        float hx = __fmul_rn(nw, 0.5f);
        float hy = __fmul_rn(nh, 0.5f);
        float4 o = make_float4(__fsub_rn(nx, hx), __fsub_rn(ny, hy),
                               __fadd_rn(nx, hx), __fadd_rn(ny, hy));
        out[i]       = o;
        sboxes[cnt]  = o;
        origIdx[cnt] = i;
    }
}

// ---------------- Kernel C: suppression bitmask, column-per-thread ----------
// thread = one column (box in regs); rows broadcast from LDS.
// Decision: t = fma(uni, -THR, inter); sign decides unless |t| <= eps*uni
// (exact IEEE division fallback -> matches numpy bit-for-bit).
// Also writes the 8-word group band per row into `band` (words 4*gr..4*gr+7,
// gr = r>>8) for the scan kernel's coalesced register prefetch.
#define M_COLS   256
#define M_RCHUNK 512
__global__ void k_mask(const float4* __restrict__ sboxes,
                       u64* __restrict__ mask,
                       u64* __restrict__ band,
                       int n, int npad, int words, int stride) {
    __shared__ __align__(16) float4 rowbox[M_RCHUNK];
    int tid = threadIdx.x;
    int c0  = blockIdx.x * M_COLS;
    int rc0 = blockIdx.y * M_RCHUNK;
    if (rc0 >= c0 + M_COLS || rc0 >= n) return;   // fully sub-diagonal / OOR

    int c = c0 + tid;
    float4 cbx = sboxes[c];
    float ca = __fmul_rn(__fsub_rn(cbx.z, cbx.x), __fsub_rn(cbx.w, cbx.y));
    int lane  = tid & 63;
    int wword = (c0 >> 6) + (tid >> 6);
    int cbase = wword << 6;

    int rlim_chunk = rc0 + M_RCHUNK; if (rlim_chunk > n) rlim_chunk = n;
    for (int j = tid; j < rlim_chunk - rc0; j += 256)
        rowbox[j] = sboxes[rc0 + j];
    __syncthreads();

    int rlim = rlim_chunk; if (rlim > cbase + 64) rlim = cbase + 64;
    for (int r = rc0; r < rlim; ++r) {
        float4 rb = rowbox[r - rc0];                       // uniform broadcast
        float ra = __fmul_rn(__fsub_rn(rb.z, rb.x), __fsub_rn(rb.w, rb.y));
        float xl = fmaxf(rb.x, cbx.x);
        float yt = fmaxf(rb.y, cbx.y);
        float xr = fminf(rb.z, cbx.z);
        float yb = fminf(rb.w, cbx.w);
        float iw = fmaxf(__fsub_rn(xr, xl), 0.0f);
        float ih = fmaxf(__fsub_rn(yb, yt), 0.0f);
        float inter = __fmul_rn(iw, ih);
        float uni = __fsub_rn(__fadd_rn(ra, ca), inter);
        float t = fmaf(uni, -THR, inter);                  // single-rounded
        bool sup = (t >= 0.0f);
        bool border = (fabsf(t) <= __fmul_rn(BORDER_EPS, uni));
        if (__any(border)) {                               // rare
            float q = inter / uni;                         // IEEE f32 div
            bool s2 = (q >= THR);
            sup = border ? s2 : sup;
        }
        u64 wvals = __ballot(sup);
        if (lane == 0) {
            u64 rmask = ~0ULL;
            if (r >= cbase) {
                int sft = r - cbase;                       // 0..63
                rmask = (sft >= 63) ? 0ULL : (~0ULL << (sft + 1));
            }
            u64 v = wvals & rmask;
            mask[(size_t)r * stride + wword] = v;
            int dd = wword - ((r >> 8) << 2);
            if ((unsigned)dd < 8u)                         // group band
                band[((size_t)r << 3) + dd] = v;
        }
    }
}

// ---------------- Kernel D: 256-row-group greedy scan -----------------------
// 40 rounds. Wave 0: in-register scan of 256 rows (D block: 4 words x 4
// row-subwords per lane; E block: next group's 4 words), readlane-driven,
// appends kept rows to LDS klist. Waves 1-3: thread 64+w owns mask word w;
// same-round batched OR of kept(g-1) full rows (vmcnt drains at the barrier
// anyway, so lagging buys nothing). W4(g) = wslot(kept<=g-2) | Eacc(kept g-1).
__device__ __forceinline__ void loadband(const u64* __restrict__ band,
                                         int gidx, int lane,
                                         u32 (&dlo)[4][4], u32 (&dhi)[4][4],
                                         u32 (&elo)[4][4], u32 (&ehi)[4][4]) {
    #pragma unroll
    for (int k = 0; k < 4; ++k) {
        size_t row = ((size_t)gidx << 8) + (k << 6) + lane;
        const ulonglong2* bp2 = (const ulonglong2*)(band + (row << 3));
        ulonglong2 q0 = bp2[0], q1 = bp2[1], q2 = bp2[2], q3 = bp2[3];
        dlo[k][0] = (u32)q0.x; dhi[k][0] = (u32)(q0.x >> 32);
        dlo[k][1] = (u32)q0.y; dhi[k][1] = (u32)(q0.y >> 32);
        dlo[k][2] = (u32)q1.x; dhi[k][2] = (u32)(q1.x >> 32);
        dlo[k][3] = (u32)q1.y; dhi[k][3] = (u32)(q1.y >> 32);
        elo[k][0] = (u32)q2.x; ehi[k][0] = (u32)(q2.x >> 32);
        elo[k][1] = (u32)q2.y; ehi[k][1] = (u32)(q2.y >> 32);
        elo[k][2] = (u32)q3.x; ehi[k][2] = (u32)(q3.x >> 32);
        elo[k][3] = (u32)q3.y; ehi[k][3] = (u32)(q3.y >> 32);
    }
}

__global__ void k_scan(const u64* __restrict__ mask,
                       const u64* __restrict__ band,
                       const int* __restrict__ origIdx,
                       float* __restrict__ keep_out,
                       int n, int words, int stride) {
    __shared__ u64 ks[160];
    __shared__ u64 wslot[8];
    __shared__ u32 klist[2][256];
    __shared__ u32 kcnt[2];
    int tid   = threadIdx.x;
    int lane  = tid & 63;
    int wv    = tid >> 6;
    int owner = tid - 64;
    int ngroups = (n + 255) >> 8;

    u64 rem = 0;
    u64 W4[4] = {0, 0, 0, 0};
    u64 Ea[4] = {0, 0, 0, 0};
    u32 DLo[4][4], DHi[4][4], ELo[4][4], EHi[4][4];
    u32 PLo[4][4], PHi[4][4], QLo[4][4], QHi[4][4];

    if (wv == 0) loadband(band, 0, lane, DLo, DHi, ELo, EHi);

    for (int g = 0; g < ngroups; ++g) {
        if (wv == 0) {
            int gp = g & 1;
            #pragma unroll
            for (int j = 0; j < 4; ++j) {
                u64 wj = (g > 0) ? wslot[(4 * g + j) & 7] : 0ULL;
                W4[j] = wj | Ea[j];
                Ea[j] = 0;
            }
            if (g + 1 < ngroups)
                loadband(band, g + 1, lane, PLo, PHi, QLo, QHi);
            u32 cnt = 0;
            #pragma unroll
            for (int s = 0; s < 4; ++s) {
                int w = 4 * g + s;
                if (w < words) {
                    int rw = w << 6;
                    int nv = n - rw; if (nv > 64) nv = 64;
                    u64 valid = (nv >= 64) ? ~0ULL
                              : ((nv <= 0) ? 0ULL : ((1ULL << nv) - 1ULL));
                    u64 cand = valid & ~W4[s];
                    while (cand) {
                        int b = (int)__builtin_ctzll(cand);
                        u64 dd[4];
                        #pragma unroll
                        for (int j = 0; j < 4; ++j) {
                            if (j >= s) {
                                dd[j] = rl64(DHi[s][j], DLo[s][j], b);
                                W4[j] |= dd[j];
                            }
                        }
                        #pragma unroll
                        for (int j = 0; j < 4; ++j)
                            Ea[j] |= rl64(EHi[s][j], ELo[s][j], b);
                        if (lane == 0) klist[gp][cnt] = (u32)((s << 6) | b);
                        ++cnt;
                        cand &= ~(dd[s] | (1ULL << b));
                    }
                    if (lane == 0) ks[w] = valid & ~W4[s];
                }
            }
            if (lane == 0) kcnt[gp] = cnt;
            if (g + 1 < ngroups) {
                #pragma unroll
                for (int k = 0; k < 4; ++k)
                    #pragma unroll
                    for (int j = 0; j < 4; ++j) {
                        DLo[k][j] = PLo[k][j]; DHi[k][j] = PHi[k][j];
                        ELo[k][j] = QLo[k][j]; EHi[k][j] = QHi[k][j];
                    }
            }
        } else if (owner >= 0 && owner < words) {
            if (g >= 1 && owner >= 4 * (g + 1)) {
                int p = (g - 1) & 1;
                u32 cnt = kcnt[p];
                const u64* rowbase =
                    mask + (((size_t)(g - 1)) << 8) * stride + owner;
                u64 t0=0,t1=0,t2=0,t3=0,t4=0,t5=0,t6=0,t7=0;
                u64 t8=0,t9=0,t10=0,t11=0,t12=0,t13=0,t14=0,t15=0;
                u64 t16=0,t17=0,t18=0,t19=0,t20=0,t21=0,t22=0,t23=0;
                u64 t24=0,t25=0,t26=0,t27=0,t28=0,t29=0,t30=0,t31=0;
#define LDK(i, ti) if ((i) < cnt) ti = rowbase[(size_t)klist[p][i] * stride];
                LDK(0,t0)   LDK(1,t1)   LDK(2,t2)   LDK(3,t3)
                LDK(4,t4)   LDK(5,t5)   LDK(6,t6)   LDK(7,t7)
                LDK(8,t8)   LDK(9,t9)   LDK(10,t10) LDK(11,t11)
                LDK(12,t12) LDK(13,t13) LDK(14,t14) LDK(15,t15)
                LDK(16,t16) LDK(17,t17) LDK(18,t18) LDK(19,t19)
                LDK(20,t20) LDK(21,t21) LDK(22,t22) LDK(23,t23)
                LDK(24,t24) LDK(25,t25) LDK(26,t26) LDK(27,t27)
                LDK(28,t28) LDK(29,t29) LDK(30,t30) LDK(31,t31)
#undef LDK
                rem |= (((t0|t1)|(t2|t3)) | ((t4|t5)|(t6|t7)))
                     | (((t8|t9)|(t10|t11)) | ((t12|t13)|(t14|t15)))
                     | (((t16|t17)|(t18|t19)) | ((t20|t21)|(t22|t23)))
                     | (((t24|t25)|(t26|t27)) | ((t28|t29)|(t30|t31)));
                for (u32 i2 = 32; i2 < cnt; ++i2)
                    rem |= rowbase[(size_t)klist[p][i2] * stride];
            }
            if ((owner >> 2) == g + 1) wslot[owner & 7] = rem;
        }
        __syncthreads();
    }

    for (int r = tid; r < n; r += 256) {
        int bit = (int)((ks[r >> 6] >> (r & 63)) & 1ULL);   // 1 = kept
        keep_out[origIdx[r]] = bit ? 1.0f : 0.0f;
    }
}

// ---------------------------------------------------------------------------
extern "C" void kernel_launch(void* const* d_in, const int* in_sizes, int n_in,
                              void* d_out, int out_size, void* d_ws, size_t ws_size,
                              hipStream_t stream) {
    const float4* boxes  = (const float4*)d_in[0];
    const float4* deltas = (const float4*)d_in[1];
    const float*  scores = (const float*)d_in[2];
    int n = in_sizes[2];                        // 10000
    int words  = (n + 63) >> 6;                 // 157
    int stride = (words + 3) & ~3;              // 160 (u64 words per row)
    int npad   = ((n + M_COLS - 1) / M_COLS) * M_COLS;  // 10240

    char* ws = (char*)d_ws;
    float4* sboxes  = (float4*)ws;                                  // npad*16
    int*    origIdx = (int*)(ws + (size_t)npad * 16);               // n*4
    size_t  moff    = ((size_t)npad * 16 + (size_t)n * 4 + 1023) & ~(size_t)1023;
    u64*    mask    = (u64*)(ws + moff);                            // n*stride*8
    size_t  msize   = (size_t)n * stride * 8;
    u64*    band    = (u64*)(ws + moff + msize);                    // npad*8*8

    float* out = (float*)d_out;

    k_rank<<<(n + 63) / 64, 256, 0, stream>>>(
        boxes, deltas, scores, (float4*)out, sboxes, origIdx, n, npad);
    dim3 mgrid(npad / M_COLS, (n + M_RCHUNK - 1) / M_RCHUNK);
    k_mask<<<mgrid, 256, 0, stream>>>(sboxes, mask, band, n, npad, words, stride);
    k_scan<<<1, 256, 0, stream>>>(mask, band, origIdx, out + (size_t)n * 4,
                                  n, words, stride);
}